// Round 1
// baseline (1303.709 us; speedup 1.0000x reference)
//
#include <hip/hip_runtime.h>
#include <hip/hip_bf16.h>

#define HD 128
#define HIDD 256
#define EPS_MSG 1e-7f
#define EPS_SM 1e-16f
#define LN_EPS 1e-5f
#define NEG_BIG -3.402823466e38f

static __device__ __forceinline__ float wave_reduce_sum(float v) {
#pragma unroll
    for (int off = 32; off >= 1; off >>= 1) v += __shfl_xor(v, off, 64);
    return v;
}

// ---------------- encoder: h = x @ enc_W + enc_b ----------------
__global__ __launch_bounds__(256) void enc_kernel(const float* __restrict__ x,
                                                  const float* __restrict__ W,
                                                  const float* __restrict__ b,
                                                  float* __restrict__ h, int N) {
    int gid = blockIdx.x * 256 + threadIdx.x;
    if (gid >= N * HD) return;
    int n = gid >> 7, c = gid & (HD - 1);
    float acc = b[c];
#pragma unroll
    for (int j = 0; j < 7; ++j) acc += x[n * 7 + j] * W[j * HD + c];
    h[gid] = acc;
}

// ---------------- CSR build ----------------
__global__ __launch_bounds__(256) void count_kernel(const int* __restrict__ dst, int* __restrict__ cnt, int E) {
    int e = blockIdx.x * 256 + threadIdx.x;
    if (e < E) atomicAdd(&cnt[dst[e]], 1);
}

__global__ __launch_bounds__(256) void scanA_kernel(const int* __restrict__ cnt, int* __restrict__ row_ptr,
                                                    int* __restrict__ blk_sums, int n) {
    __shared__ int sb[256];
    int tid = threadIdx.x;
    int idx = blockIdx.x * 256 + tid;
    int v = (idx < n) ? cnt[idx] : 0;
    sb[tid] = v;
    __syncthreads();
#pragma unroll
    for (int off = 1; off < 256; off <<= 1) {
        int x = (tid >= off) ? sb[tid - off] : 0;
        __syncthreads();
        sb[tid] += x;
        __syncthreads();
    }
    if (idx < n) row_ptr[idx + 1] = sb[tid];
    if (tid == 255) blk_sums[blockIdx.x] = sb[255];
}

__global__ __launch_bounds__(256) void scanB_kernel(int* __restrict__ blk_sums, int nblk) {
    __shared__ int sb[256];
    int tid = threadIdx.x;
    int v = (tid < nblk) ? blk_sums[tid] : 0;
    sb[tid] = v;
    __syncthreads();
#pragma unroll
    for (int off = 1; off < 256; off <<= 1) {
        int x = (tid >= off) ? sb[tid - off] : 0;
        __syncthreads();
        sb[tid] += x;
        __syncthreads();
    }
    if (tid < nblk) blk_sums[tid] = sb[tid];
}

__global__ __launch_bounds__(256) void scanC_kernel(int* __restrict__ row_ptr, const int* __restrict__ blk_sums, int n) {
    int idx = blockIdx.x * 256 + threadIdx.x;
    if (idx == 0) row_ptr[0] = 0;
    if (idx < n) {
        int b = idx >> 8;
        if (b > 0) row_ptr[idx + 1] += blk_sums[b - 1];
    }
}

__global__ __launch_bounds__(256) void cursor_init_kernel(const int* __restrict__ row_ptr, int* __restrict__ cursor, int n) {
    int idx = blockIdx.x * 256 + threadIdx.x;
    if (idx < n) cursor[idx] = row_ptr[idx];
}

__global__ __launch_bounds__(256) void scatter_kernel(const int* __restrict__ src, const int* __restrict__ dst,
                                                      int* __restrict__ cursor, int* __restrict__ esrc, int E) {
    int e = blockIdx.x * 256 + threadIdx.x;
    if (e < E) {
        int v = dst[e];
        int pos = atomicAdd(&cursor[v], 1);
        esrc[pos] = src[e];
    }
}

// ---------------- pre-layer LN + ReLU: z = relu(LN(h)) ----------------
__global__ __launch_bounds__(256) void ln_relu_kernel(const float* __restrict__ h,
                                                      const float* __restrict__ g,
                                                      const float* __restrict__ b,
                                                      float* __restrict__ z, int N) {
    int node = blockIdx.x * 4 + (threadIdx.x >> 6);
    int lane = threadIdx.x & 63;
    if (node >= N) return;
    const float* hr = h + (size_t)node * HD;
    float v0 = hr[lane], v1 = hr[lane + 64];
    float s = wave_reduce_sum(v0 + v1);
    float ss = wave_reduce_sum(v0 * v0 + v1 * v1);
    float mu = s * (1.f / 128.f);
    float var = ss * (1.f / 128.f) - mu * mu;
    float rstd = rsqrtf(var + LN_EPS);
    float z0 = fmaxf((v0 - mu) * rstd * g[lane] + b[lane], 0.f);
    float z1 = fmaxf((v1 - mu) * rstd * g[lane + 64] + b[lane + 64], 0.f);
    size_t base = (size_t)node * HD;
    z[base + lane] = z0;
    z[base + lane + 64] = z1;
}

// ---------------- aggregation: out = softmax-agg(z[src] + eps over dst) + z ----------------
__global__ __launch_bounds__(256) void agg_kernel(const float* __restrict__ z,
                                                  const int* __restrict__ row_ptr,
                                                  const int* __restrict__ esrc,
                                                  const float* __restrict__ t_all, int layer,
                                                  float* __restrict__ obuf, int N) {
    int node = blockIdx.x * 4 + (threadIdx.x >> 6);
    int lane = threadIdx.x & 63;
    if (node >= N) return;
    float tv = t_all[layer];
    int beg = row_ptr[node], end = row_ptr[node + 1];
    float m0 = NEG_BIG, m1 = NEG_BIG;
    float se0 = 0.f, se1 = 0.f, sw0 = 0.f, sw1 = 0.f;
    for (int e = beg; e < end; ++e) {
        int sidx = esrc[e];
        const float* zr = z + (size_t)sidx * HD;
        float msg0 = zr[lane] + EPS_MSG;
        float msg1 = zr[lane + 64] + EPS_MSG;
        float l0 = msg0 * tv, l1 = msg1 * tv;
        float nm0 = fmaxf(m0, l0), nm1 = fmaxf(m1, l1);
        float sc0 = __expf(m0 - nm0), sc1 = __expf(m1 - nm1);
        float e0 = __expf(l0 - nm0), e1 = __expf(l1 - nm1);
        se0 = se0 * sc0 + e0;
        sw0 = sw0 * sc0 + e0 * msg0;
        se1 = se1 * sc1 + e1;
        sw1 = sw1 * sc1 + e1 * msg1;
        m0 = nm0;
        m1 = nm1;
    }
    float a0 = (end > beg) ? sw0 / (se0 + EPS_SM) : 0.f;
    float a1 = (end > beg) ? sw1 / (se1 + EPS_SM) : 0.f;
    size_t base = (size_t)node * HD;
    obuf[base + lane] = a0 + z[base + lane];
    obuf[base + lane + 64] = a1 + z[base + lane + 64];
}

// ---------------- fused MLP: h += relu(LN(obuf@W1+b1))@W2 + b2 ----------------
__global__ __launch_bounds__(256) void mlp_kernel(const float* __restrict__ obuf,
                                                  float* __restrict__ h,
                                                  const float* __restrict__ W1, const float* __restrict__ b1,
                                                  const float* __restrict__ g1, const float* __restrict__ bb1,
                                                  const float* __restrict__ W2, const float* __restrict__ b2,
                                                  int N) {
    __shared__ float s_in[16 * 128];
    __shared__ float s_u[16 * 256];
    int tid = threadIdx.x;
    int row0 = blockIdx.x * 16;

    // stage 16 input rows
    for (int i = tid; i < 16 * 128; i += 256) {
        int r = i >> 7;
        int row = row0 + r;
        s_in[i] = (row < N) ? obuf[(size_t)row * HD + (i & 127)] : 0.f;
    }
    __syncthreads();

    // GEMM1: u = in @ W1 + b1  (thread owns cols ca, ca+128; rows rbase..rbase+7)
    int ca = tid & 127, cb = ca + 128;
    int rbase = (tid >> 7) * 8;
    float accA[8], accB[8];
#pragma unroll
    for (int r = 0; r < 8; ++r) { accA[r] = 0.f; accB[r] = 0.f; }
    for (int k = 0; k < 128; k += 4) {
        float wa0 = W1[(k + 0) * HIDD + ca];
        float wa1 = W1[(k + 1) * HIDD + ca];
        float wa2 = W1[(k + 2) * HIDD + ca];
        float wa3 = W1[(k + 3) * HIDD + ca];
        float wb0 = W1[(k + 0) * HIDD + cb];
        float wb1 = W1[(k + 1) * HIDD + cb];
        float wb2 = W1[(k + 2) * HIDD + cb];
        float wb3 = W1[(k + 3) * HIDD + cb];
#pragma unroll
        for (int r = 0; r < 8; ++r) {
            const float4 a = *(const float4*)&s_in[(rbase + r) * 128 + k];
            accA[r] += a.x * wa0 + a.y * wa1 + a.z * wa2 + a.w * wa3;
            accB[r] += a.x * wb0 + a.y * wb1 + a.z * wb2 + a.w * wb3;
        }
    }
    float b1a = b1[ca], b1b = b1[cb];
#pragma unroll
    for (int r = 0; r < 8; ++r) {
        s_u[(rbase + r) * 256 + ca] = accA[r] + b1a;
        s_u[(rbase + r) * 256 + cb] = accB[r] + b1b;
    }
    __syncthreads();

    // LN over 256 + ReLU, 4 waves x 4 rows
    int wave = tid >> 6, lane = tid & 63;
#pragma unroll
    for (int rr = 0; rr < 4; ++rr) {
        int r = wave * 4 + rr;
        float v0 = s_u[r * 256 + lane];
        float v1 = s_u[r * 256 + 64 + lane];
        float v2 = s_u[r * 256 + 128 + lane];
        float v3 = s_u[r * 256 + 192 + lane];
        float s = wave_reduce_sum(v0 + v1 + v2 + v3);
        float ss = wave_reduce_sum(v0 * v0 + v1 * v1 + v2 * v2 + v3 * v3);
        float mu = s * (1.f / 256.f);
        float var = ss * (1.f / 256.f) - mu * mu;
        float rstd = rsqrtf(var + LN_EPS);
        float o0 = fmaxf((v0 - mu) * rstd * g1[lane] + bb1[lane], 0.f);
        float o1 = fmaxf((v1 - mu) * rstd * g1[lane + 64] + bb1[lane + 64], 0.f);
        float o2 = fmaxf((v2 - mu) * rstd * g1[lane + 128] + bb1[lane + 128], 0.f);
        float o3 = fmaxf((v3 - mu) * rstd * g1[lane + 192] + bb1[lane + 192], 0.f);
        s_u[r * 256 + lane] = o0;
        s_u[r * 256 + 64 + lane] = o1;
        s_u[r * 256 + 128 + lane] = o2;
        s_u[r * 256 + 192 + lane] = o3;
    }
    __syncthreads();

    // GEMM2: h += hm @ W2 + b2 (thread owns col c2=ca, rows rbase..rbase+7)
    int c2 = ca;
    float acc2[8];
#pragma unroll
    for (int r = 0; r < 8; ++r) acc2[r] = 0.f;
    for (int k = 0; k < 256; k += 4) {
        float w0 = W2[(k + 0) * HD + c2];
        float w1 = W2[(k + 1) * HD + c2];
        float w2 = W2[(k + 2) * HD + c2];
        float w3 = W2[(k + 3) * HD + c2];
#pragma unroll
        for (int r = 0; r < 8; ++r) {
            const float4 a = *(const float4*)&s_u[(rbase + r) * 256 + k];
            acc2[r] += a.x * w0 + a.y * w1 + a.z * w2 + a.w * w3;
        }
    }
    float b2c = b2[c2];
#pragma unroll
    for (int r = 0; r < 8; ++r) {
        int row = row0 + rbase + r;
        if (row < N) h[(size_t)row * HD + c2] += acc2[r] + b2c;
    }
}

// ---------------- pooling (sorted batch) ----------------
__global__ __launch_bounds__(256) void pool_kernel(const float* __restrict__ h,
                                                   const int* __restrict__ batch, int N,
                                                   float* __restrict__ pooled) {
    __shared__ int sb[2];
    __shared__ float red[256];
    int g = blockIdx.x;
    if (threadIdx.x == 0) {
        int lo = 0, hi = N;
        while (lo < hi) { int mid = (lo + hi) >> 1; if (batch[mid] < g) lo = mid + 1; else hi = mid; }
        sb[0] = lo;
        lo = 0; hi = N;
        int gq = g + 1;
        while (lo < hi) { int mid = (lo + hi) >> 1; if (batch[mid] < gq) lo = mid + 1; else hi = mid; }
        sb[1] = lo;
    }
    __syncthreads();
    int beg = sb[0], end = sb[1];
    int c = threadIdx.x & 127, half = threadIdx.x >> 7;
    float acc = 0.f;
    for (int r = beg + half; r < end; r += 2) acc += h[(size_t)r * HD + c];
    red[threadIdx.x] = acc;
    __syncthreads();
    if (half == 0) pooled[(size_t)g * HD + c] = red[c] + red[128 + c];
}

// ---------------- classifier ----------------
__global__ __launch_bounds__(256) void cls_kernel(const float* __restrict__ pooled,
                                                  const float* __restrict__ W,
                                                  const float* __restrict__ b,
                                                  float* __restrict__ out, int G) {
    int gid = blockIdx.x * 256 + threadIdx.x;
    if (gid >= G * 2) return;
    int g = gid >> 1, cl = gid & 1;
    float acc = b[cl];
#pragma unroll 8
    for (int k = 0; k < HD; ++k) acc += pooled[g * HD + k] * W[k * 2 + cl];
    out[gid] = acc;
}

extern "C" void kernel_launch(void* const* d_in, const int* in_sizes, int n_in,
                              void* d_out, int out_size, void* d_ws, size_t ws_size,
                              hipStream_t stream) {
    const float* x     = (const float*)d_in[0];
    const int*   eidx  = (const int*)d_in[1];
    const int*   batch = (const int*)d_in[2];
    const float* enc_W = (const float*)d_in[3];
    const float* enc_b = (const float*)d_in[4];
    const float* t_all = (const float*)d_in[5];
    const float* W1    = (const float*)d_in[6];
    const float* b1    = (const float*)d_in[7];
    const float* g1    = (const float*)d_in[8];
    const float* bb1   = (const float*)d_in[9];
    const float* W2    = (const float*)d_in[10];
    const float* b2    = (const float*)d_in[11];
    const float* ln_g  = (const float*)d_in[12];
    const float* ln_b  = (const float*)d_in[13];
    const float* cls_W = (const float*)d_in[14];
    const float* cls_b = (const float*)d_in[15];
    float* out = (float*)d_out;

    const int N = in_sizes[0] / 7;
    const int E = in_sizes[1] / 2;
    const int L = in_sizes[5];
    const int G = out_size / 2;
    const int* src = eidx;
    const int* dst = eidx + E;

    // workspace carve (256B aligned)
    char* p = (char*)d_ws;
    auto alloc = [&](size_t bytes) {
        char* q = p;
        p += (bytes + 255) & ~(size_t)255;
        return q;
    };
    float* h      = (float*)alloc((size_t)N * HD * 4);
    float* z      = (float*)alloc((size_t)N * HD * 4);
    float* obuf   = (float*)alloc((size_t)N * HD * 4);
    float* pooled = (float*)alloc((size_t)G * HD * 4);
    int* cnt      = (int*)alloc((size_t)N * 4);
    int* row_ptr  = (int*)alloc((size_t)(N + 1) * 4);
    int* cursor   = (int*)alloc((size_t)N * 4);
    int* blk_sums = (int*)alloc(256 * 4);
    int* esrc     = (int*)alloc((size_t)E * 4);

    const int nblkN = (N + 255) / 256;
    const int nblkE = (E + 255) / 256;

    // encoder
    enc_kernel<<<(N * HD + 255) / 256, 256, 0, stream>>>(x, enc_W, enc_b, h, N);

    // CSR build
    hipMemsetAsync(cnt, 0, (size_t)N * 4, stream);
    count_kernel<<<nblkE, 256, 0, stream>>>(dst, cnt, E);
    scanA_kernel<<<nblkN, 256, 0, stream>>>(cnt, row_ptr, blk_sums, N);
    scanB_kernel<<<1, 256, 0, stream>>>(blk_sums, nblkN);
    scanC_kernel<<<nblkN, 256, 0, stream>>>(row_ptr, blk_sums, N);
    cursor_init_kernel<<<nblkN, 256, 0, stream>>>(row_ptr, cursor, N);
    scatter_kernel<<<nblkE, 256, 0, stream>>>(src, dst, cursor, esrc, E);

    // layers
    for (int i = 0; i < L; ++i) {
        ln_relu_kernel<<<(N + 3) / 4, 256, 0, stream>>>(h, ln_g + i * HD, ln_b + i * HD, z, N);
        agg_kernel<<<(N + 3) / 4, 256, 0, stream>>>(z, row_ptr, esrc, t_all, i, obuf, N);
        mlp_kernel<<<(N + 15) / 16, 256, 0, stream>>>(obuf, h,
                                                      W1 + (size_t)i * HD * HIDD, b1 + (size_t)i * HIDD,
                                                      g1 + (size_t)i * HIDD, bb1 + (size_t)i * HIDD,
                                                      W2 + (size_t)i * HIDD * HD, b2 + (size_t)i * HD,
                                                      N);
    }

    // pooling + classifier
    pool_kernel<<<G, 256, 0, stream>>>(h, batch, N, pooled);
    cls_kernel<<<(G * 2 + 255) / 256, 256, 0, stream>>>(pooled, cls_W, cls_b, out, G);
}

// Round 2
// 750.664 us; speedup vs baseline: 1.7367x; 1.7367x over previous
//
#include <hip/hip_runtime.h>
#include <hip/hip_bf16.h>

#define HD 128
#define HIDD 256
#define EPS_MSG 1e-7f
#define EPS_SM 1e-16f
#define LN_EPS 1e-5f
#define NEG_BIG -3.402823466e38f
#define AP 136   // A_lds row stride (bf16 elems): 128+8 -> 2-way bank alias (free)
#define HP 264   // hm_lds row stride (bf16 elems): 256+8

typedef __attribute__((ext_vector_type(8))) short bf16x8;
typedef __attribute__((ext_vector_type(4))) float f32x4;

static __device__ __forceinline__ float wave_reduce_sum(float v) {
#pragma unroll
    for (int off = 32; off >= 1; off >>= 1) v += __shfl_xor(v, off, 64);
    return v;
}

static __device__ __forceinline__ float bf2f(ushort u) {
    union { float f; unsigned v; } x;
    x.v = ((unsigned)u) << 16;
    return x.f;
}
static __device__ __forceinline__ ushort f2bf(float f) {
    __hip_bfloat16 b = __float2bfloat16(f);
    return *(ushort*)&b;
}

// ---------------- encoder: h = x @ enc_W + enc_b ----------------
__global__ __launch_bounds__(256) void enc_kernel(const float* __restrict__ x,
                                                  const float* __restrict__ W,
                                                  const float* __restrict__ b,
                                                  float* __restrict__ h, int N) {
    int gid = blockIdx.x * 256 + threadIdx.x;
    if (gid >= N * HD) return;
    int n = gid >> 7, c = gid & (HD - 1);
    float acc = b[c];
#pragma unroll
    for (int j = 0; j < 7; ++j) acc += x[n * 7 + j] * W[j * HD + c];
    h[gid] = acc;
}

// ---------------- weight convert + transpose to bf16 ----------------
// W1t[l][n][k] = bf16(W1[l][k][n])  (n<256,k<128);  W2t[l][n][k] = bf16(W2[l][k][n]) (n<128,k<256)
__global__ __launch_bounds__(256) void wconv_kernel(const float* __restrict__ W1,
                                                    const float* __restrict__ W2,
                                                    ushort* __restrict__ W1t,
                                                    ushort* __restrict__ W2t, int L) {
    int gid = blockIdx.x * 256 + threadIdx.x;
    int per = HD * HIDD;  // 32768
    int tot = L * per;
    if (gid < tot) {
        int l = gid / per, r = gid % per;
        int n = r >> 7, k = r & 127;  // n<256, k<128
        W1t[gid] = f2bf(W1[(size_t)l * per + (size_t)k * HIDD + n]);
    } else if (gid < 2 * tot) {
        int g2 = gid - tot;
        int l = g2 / per, r = g2 % per;
        int n = r >> 8, k = r & 255;  // n<128, k<256
        W2t[g2] = f2bf(W2[(size_t)l * per + (size_t)k * HD + n]);
    }
}

// ---------------- CSR build ----------------
__global__ __launch_bounds__(256) void count_kernel(const int* __restrict__ dst, int* __restrict__ cnt, int E) {
    int e = blockIdx.x * 256 + threadIdx.x;
    if (e < E) atomicAdd(&cnt[dst[e]], 1);
}

__global__ __launch_bounds__(256) void scanA_kernel(const int* __restrict__ cnt, int* __restrict__ row_ptr,
                                                    int* __restrict__ blk_sums, int n) {
    __shared__ int sb[256];
    int tid = threadIdx.x;
    int idx = blockIdx.x * 256 + tid;
    int v = (idx < n) ? cnt[idx] : 0;
    sb[tid] = v;
    __syncthreads();
#pragma unroll
    for (int off = 1; off < 256; off <<= 1) {
        int x = (tid >= off) ? sb[tid - off] : 0;
        __syncthreads();
        sb[tid] += x;
        __syncthreads();
    }
    if (idx < n) row_ptr[idx + 1] = sb[tid];
    if (tid == 255) blk_sums[blockIdx.x] = sb[255];
}

__global__ __launch_bounds__(256) void scanB_kernel(int* __restrict__ blk_sums, int nblk) {
    __shared__ int sb[256];
    int tid = threadIdx.x;
    int v = (tid < nblk) ? blk_sums[tid] : 0;
    sb[tid] = v;
    __syncthreads();
#pragma unroll
    for (int off = 1; off < 256; off <<= 1) {
        int x = (tid >= off) ? sb[tid - off] : 0;
        __syncthreads();
        sb[tid] += x;
        __syncthreads();
    }
    if (tid < nblk) blk_sums[tid] = sb[tid];
}

__global__ __launch_bounds__(256) void scanC_kernel(int* __restrict__ row_ptr, const int* __restrict__ blk_sums, int n) {
    int idx = blockIdx.x * 256 + threadIdx.x;
    if (idx == 0) row_ptr[0] = 0;
    if (idx < n) {
        int b = idx >> 8;
        if (b > 0) row_ptr[idx + 1] += blk_sums[b - 1];
    }
}

__global__ __launch_bounds__(256) void cursor_init_kernel(const int* __restrict__ row_ptr, int* __restrict__ cursor, int n) {
    int idx = blockIdx.x * 256 + threadIdx.x;
    if (idx < n) cursor[idx] = row_ptr[idx];
}

__global__ __launch_bounds__(256) void scatter_kernel(const int* __restrict__ src, const int* __restrict__ dst,
                                                      int* __restrict__ cursor, int* __restrict__ esrc, int E) {
    int e = blockIdx.x * 256 + threadIdx.x;
    if (e < E) {
        int v = dst[e];
        int pos = atomicAdd(&cursor[v], 1);
        esrc[pos] = src[e];
    }
}

// ---------------- pre-layer LN + ReLU: z = relu(LN(h))  (z stored bf16) ----------------
__global__ __launch_bounds__(256) void ln_relu_kernel(const float* __restrict__ h,
                                                      const float* __restrict__ g,
                                                      const float* __restrict__ b,
                                                      ushort* __restrict__ z, int N) {
    int node = blockIdx.x * 4 + (threadIdx.x >> 6);
    int lane = threadIdx.x & 63;
    if (node >= N) return;
    const float* hr = h + (size_t)node * HD;
    float v0 = hr[lane], v1 = hr[lane + 64];
    float s = wave_reduce_sum(v0 + v1);
    float ss = wave_reduce_sum(v0 * v0 + v1 * v1);
    float mu = s * (1.f / 128.f);
    float var = ss * (1.f / 128.f) - mu * mu;
    float rstd = rsqrtf(var + LN_EPS);
    float z0 = fmaxf((v0 - mu) * rstd * g[lane] + b[lane], 0.f);
    float z1 = fmaxf((v1 - mu) * rstd * g[lane + 64] + b[lane + 64], 0.f);
    size_t base = (size_t)node * HD;
    z[base + lane] = f2bf(z0);
    z[base + lane + 64] = f2bf(z1);
}

// ---------------- aggregation: obuf = softmax-agg(z[src]+eps over dst) + z  (bf16 in/out) ----------------
__global__ __launch_bounds__(256) void agg_kernel(const ushort* __restrict__ z,
                                                  const int* __restrict__ row_ptr,
                                                  const int* __restrict__ esrc,
                                                  const float* __restrict__ t_all, int layer,
                                                  ushort* __restrict__ obuf, int N) {
    int node = blockIdx.x * 4 + (threadIdx.x >> 6);
    int lane = threadIdx.x & 63;
    if (node >= N) return;
    float tv = t_all[layer];
    int beg = row_ptr[node], end = row_ptr[node + 1];
    float m0 = NEG_BIG, m1 = NEG_BIG;
    float se0 = 0.f, se1 = 0.f, sw0 = 0.f, sw1 = 0.f;
    for (int e = beg; e < end; ++e) {
        int sidx = esrc[e];
        const ushort* zr = z + (size_t)sidx * HD;
        float msg0 = bf2f(zr[lane]) + EPS_MSG;
        float msg1 = bf2f(zr[lane + 64]) + EPS_MSG;
        float l0 = msg0 * tv, l1 = msg1 * tv;
        float nm0 = fmaxf(m0, l0), nm1 = fmaxf(m1, l1);
        float sc0 = __expf(m0 - nm0), sc1 = __expf(m1 - nm1);
        float e0 = __expf(l0 - nm0), e1 = __expf(l1 - nm1);
        se0 = se0 * sc0 + e0;
        sw0 = sw0 * sc0 + e0 * msg0;
        se1 = se1 * sc1 + e1;
        sw1 = sw1 * sc1 + e1 * msg1;
        m0 = nm0;
        m1 = nm1;
    }
    float a0 = (end > beg) ? sw0 / (se0 + EPS_SM) : 0.f;
    float a1 = (end > beg) ? sw1 / (se1 + EPS_SM) : 0.f;
    size_t base = (size_t)node * HD;
    obuf[base + lane] = f2bf(a0 + bf2f(z[base + lane]));
    obuf[base + lane + 64] = f2bf(a1 + bf2f(z[base + lane + 64]));
}

// ---------------- fused MFMA MLP: h += relu(LN(obuf@W1+b1))@W2 + b2 ----------------
// 64-row tile, 4 waves; GEMM1 wave w -> cols [w*64, w*64+64); GEMM2 wave w -> cols [w*32, w*32+32)
__global__ __launch_bounds__(256) void mlp_kernel(const ushort* __restrict__ obuf,
                                                  float* __restrict__ h,
                                                  const ushort* __restrict__ W1t, const float* __restrict__ b1,
                                                  const float* __restrict__ g1, const float* __restrict__ bb1,
                                                  const ushort* __restrict__ W2t, const float* __restrict__ b2,
                                                  int N) {
    __shared__ ushort s_a[64 * AP];    // 17408 B
    __shared__ ushort s_hm[64 * HP];   // 33792 B
    __shared__ float s_part[64 * 8];   // 2048 B : [row][wave][{sum,sumsq}]

    int tid = threadIdx.x;
    int row0 = blockIdx.x * 64;
    int wid = tid >> 6, lane = tid & 63;
    int l15 = lane & 15, q = lane >> 4;

    // ---- stage A tile (64 x 128 bf16) ----
#pragma unroll
    for (int i = 0; i < 4; ++i) {
        int c = tid + i * 256;           // chunk id < 1024
        int r = c >> 4, col8 = (c & 15) * 8;
        bf16x8 v;
        if (row0 + r < N) {
            v = *(const bf16x8*)(obuf + (size_t)(row0 + r) * HD + col8);
        } else {
            v = (bf16x8)0;
        }
        *(bf16x8*)&s_a[r * AP + col8] = v;
    }
    __syncthreads();

    // ---- GEMM1: u = A @ W1 + b1 ----
    f32x4 acc1[4][4];
#pragma unroll
    for (int mb = 0; mb < 4; ++mb)
#pragma unroll
        for (int nb = 0; nb < 4; ++nb) acc1[mb][nb] = (f32x4)0.f;

#pragma unroll
    for (int kk = 0; kk < 4; ++kk) {
        bf16x8 af[4];
#pragma unroll
        for (int mb = 0; mb < 4; ++mb)
            af[mb] = *(const bf16x8*)&s_a[(mb * 16 + l15) * AP + kk * 32 + q * 8];
#pragma unroll
        for (int nb = 0; nb < 4; ++nb) {
            int col = wid * 64 + nb * 16 + l15;
            bf16x8 bf = *(const bf16x8*)&W1t[(size_t)col * HD + kk * 32 + q * 8];
#pragma unroll
            for (int mb = 0; mb < 4; ++mb)
                acc1[mb][nb] = __builtin_amdgcn_mfma_f32_16x16x32_bf16(af[mb], bf, acc1[mb][nb], 0, 0, 0);
        }
    }

    // add b1, per-lane col params
    float b1c[4], g1c[4], bbc[4];
#pragma unroll
    for (int nb = 0; nb < 4; ++nb) {
        int col = wid * 64 + nb * 16 + l15;
        b1c[nb] = b1[col];
        g1c[nb] = g1[col];
        bbc[nb] = bb1[col];
#pragma unroll
        for (int mb = 0; mb < 4; ++mb) {
#pragma unroll
            for (int rg = 0; rg < 4; ++rg) acc1[mb][nb][rg] += b1c[nb];
        }
    }

    // ---- LN partial sums (per wave: 64 cols) ----
#pragma unroll
    for (int mb = 0; mb < 4; ++mb) {
#pragma unroll
        for (int rg = 0; rg < 4; ++rg) {
            float s = acc1[mb][0][rg] + acc1[mb][1][rg] + acc1[mb][2][rg] + acc1[mb][3][rg];
            float ss = acc1[mb][0][rg] * acc1[mb][0][rg] + acc1[mb][1][rg] * acc1[mb][1][rg] +
                       acc1[mb][2][rg] * acc1[mb][2][rg] + acc1[mb][3][rg] * acc1[mb][3][rg];
#pragma unroll
            for (int m = 1; m <= 8; m <<= 1) {
                s += __shfl_xor(s, m, 64);
                ss += __shfl_xor(ss, m, 64);
            }
            if (l15 == 0) {
                int r = mb * 16 + q * 4 + rg;
                s_part[r * 8 + wid * 2] = s;
                s_part[r * 8 + wid * 2 + 1] = ss;
            }
        }
    }
    __syncthreads();

    // ---- finish LN + ReLU, write hm bf16 to LDS ----
#pragma unroll
    for (int mb = 0; mb < 4; ++mb) {
#pragma unroll
        for (int rg = 0; rg < 4; ++rg) {
            int r = mb * 16 + q * 4 + rg;
            f32x4 p0 = *(const f32x4*)&s_part[r * 8];
            f32x4 p1 = *(const f32x4*)&s_part[r * 8 + 4];
            float S = p0.x + p0.z + p1.x + p1.z;
            float SS = p0.y + p0.w + p1.y + p1.w;
            float mu = S * (1.f / 256.f);
            float var = SS * (1.f / 256.f) - mu * mu;
            float rstd = rsqrtf(var + LN_EPS);
#pragma unroll
            for (int nb = 0; nb < 4; ++nb) {
                float v = (acc1[mb][nb][rg] - mu) * rstd * g1c[nb] + bbc[nb];
                v = fmaxf(v, 0.f);
                s_hm[r * HP + wid * 64 + nb * 16 + l15] = f2bf(v);
            }
        }
    }
    __syncthreads();

    // ---- GEMM2: out = hm @ W2 ----
    f32x4 acc2[4][2];
#pragma unroll
    for (int mb = 0; mb < 4; ++mb)
#pragma unroll
        for (int nb = 0; nb < 2; ++nb) acc2[mb][nb] = (f32x4)0.f;

#pragma unroll
    for (int kk = 0; kk < 8; ++kk) {
        bf16x8 af2[4];
#pragma unroll
        for (int mb = 0; mb < 4; ++mb)
            af2[mb] = *(const bf16x8*)&s_hm[(mb * 16 + l15) * HP + kk * 32 + q * 8];
#pragma unroll
        for (int nb = 0; nb < 2; ++nb) {
            int col = wid * 32 + nb * 16 + l15;
            bf16x8 bf = *(const bf16x8*)&W2t[(size_t)col * HIDD + kk * 32 + q * 8];
#pragma unroll
            for (int mb = 0; mb < 4; ++mb)
                acc2[mb][nb] = __builtin_amdgcn_mfma_f32_16x16x32_bf16(af2[mb], bf, acc2[mb][nb], 0, 0, 0);
        }
    }

    // ---- epilogue: h += out + b2 ----
#pragma unroll
    for (int nb = 0; nb < 2; ++nb) {
        int col = wid * 32 + nb * 16 + l15;
        float b2c = b2[col];
#pragma unroll
        for (int mb = 0; mb < 4; ++mb) {
#pragma unroll
            for (int rg = 0; rg < 4; ++rg) {
                int row = row0 + mb * 16 + q * 4 + rg;
                if (row < N) h[(size_t)row * HD + col] += acc2[mb][nb][rg] + b2c;
            }
        }
    }
}

// ---------------- pooling (sorted batch) ----------------
__global__ __launch_bounds__(256) void pool_kernel(const float* __restrict__ h,
                                                   const int* __restrict__ batch, int N,
                                                   float* __restrict__ pooled) {
    __shared__ int sb[2];
    __shared__ float red[256];
    int g = blockIdx.x;
    if (threadIdx.x == 0) {
        int lo = 0, hi = N;
        while (lo < hi) { int mid = (lo + hi) >> 1; if (batch[mid] < g) lo = mid + 1; else hi = mid; }
        sb[0] = lo;
        lo = 0; hi = N;
        int gq = g + 1;
        while (lo < hi) { int mid = (lo + hi) >> 1; if (batch[mid] < gq) lo = mid + 1; else hi = mid; }
        sb[1] = lo;
    }
    __syncthreads();
    int beg = sb[0], end = sb[1];
    int c = threadIdx.x & 127, half = threadIdx.x >> 7;
    float acc = 0.f;
    for (int r = beg + half; r < end; r += 2) acc += h[(size_t)r * HD + c];
    red[threadIdx.x] = acc;
    __syncthreads();
    if (half == 0) pooled[(size_t)g * HD + c] = red[c] + red[128 + c];
}

// ---------------- classifier ----------------
__global__ __launch_bounds__(256) void cls_kernel(const float* __restrict__ pooled,
                                                  const float* __restrict__ W,
                                                  const float* __restrict__ b,
                                                  float* __restrict__ out, int G) {
    int gid = blockIdx.x * 256 + threadIdx.x;
    if (gid >= G * 2) return;
    int g = gid >> 1, cl = gid & 1;
    float acc = b[cl];
#pragma unroll 8
    for (int k = 0; k < HD; ++k) acc += pooled[g * HD + k] * W[k * 2 + cl];
    out[gid] = acc;
}

extern "C" void kernel_launch(void* const* d_in, const int* in_sizes, int n_in,
                              void* d_out, int out_size, void* d_ws, size_t ws_size,
                              hipStream_t stream) {
    const float* x     = (const float*)d_in[0];
    const int*   eidx  = (const int*)d_in[1];
    const int*   batch = (const int*)d_in[2];
    const float* enc_W = (const float*)d_in[3];
    const float* enc_b = (const float*)d_in[4];
    const float* t_all = (const float*)d_in[5];
    const float* W1    = (const float*)d_in[6];
    const float* b1    = (const float*)d_in[7];
    const float* g1    = (const float*)d_in[8];
    const float* bb1   = (const float*)d_in[9];
    const float* W2    = (const float*)d_in[10];
    const float* b2    = (const float*)d_in[11];
    const float* ln_g  = (const float*)d_in[12];
    const float* ln_b  = (const float*)d_in[13];
    const float* cls_W = (const float*)d_in[14];
    const float* cls_b = (const float*)d_in[15];
    float* out = (float*)d_out;

    const int N = in_sizes[0] / 7;
    const int E = in_sizes[1] / 2;
    const int L = in_sizes[5];
    const int G = out_size / 2;
    const int* src = eidx;
    const int* dst = eidx + E;

    // workspace carve (256B aligned)
    char* p = (char*)d_ws;
    auto alloc = [&](size_t bytes) {
        char* q = p;
        p += (bytes + 255) & ~(size_t)255;
        return q;
    };
    float*  h      = (float*)alloc((size_t)N * HD * 4);
    ushort* z      = (ushort*)alloc((size_t)N * HD * 2);
    ushort* obuf   = (ushort*)alloc((size_t)N * HD * 2);
    float*  pooled = (float*)alloc((size_t)G * HD * 4);
    int* cnt      = (int*)alloc((size_t)N * 4);
    int* row_ptr  = (int*)alloc((size_t)(N + 1) * 4);
    int* cursor   = (int*)alloc((size_t)N * 4);
    int* blk_sums = (int*)alloc(256 * 4);
    int* esrc     = (int*)alloc((size_t)E * 4);
    ushort* W1t   = (ushort*)alloc((size_t)L * HD * HIDD * 2);
    ushort* W2t   = (ushort*)alloc((size_t)L * HD * HIDD * 2);

    const int nblkN = (N + 255) / 256;
    const int nblkE = (E + 255) / 256;

    // encoder + weight conversion
    enc_kernel<<<(N * HD + 255) / 256, 256, 0, stream>>>(x, enc_W, enc_b, h, N);
    {
        int tot2 = 2 * L * HD * HIDD;
        wconv_kernel<<<(tot2 + 255) / 256, 256, 0, stream>>>(W1, W2, W1t, W2t, L);
    }

    // CSR build
    hipMemsetAsync(cnt, 0, (size_t)N * 4, stream);
    count_kernel<<<nblkE, 256, 0, stream>>>(dst, cnt, E);
    scanA_kernel<<<nblkN, 256, 0, stream>>>(cnt, row_ptr, blk_sums, N);
    scanB_kernel<<<1, 256, 0, stream>>>(blk_sums, nblkN);
    scanC_kernel<<<nblkN, 256, 0, stream>>>(row_ptr, blk_sums, N);
    cursor_init_kernel<<<nblkN, 256, 0, stream>>>(row_ptr, cursor, N);
    scatter_kernel<<<nblkE, 256, 0, stream>>>(src, dst, cursor, esrc, E);

    // layers
    for (int i = 0; i < L; ++i) {
        ln_relu_kernel<<<(N + 3) / 4, 256, 0, stream>>>(h, ln_g + i * HD, ln_b + i * HD, z, N);
        agg_kernel<<<(N + 3) / 4, 256, 0, stream>>>(z, row_ptr, esrc, t_all, i, obuf, N);
        mlp_kernel<<<(N + 63) / 64, 256, 0, stream>>>(obuf, h,
                                                      W1t + (size_t)i * HD * HIDD, b1 + (size_t)i * HIDD,
                                                      g1 + (size_t)i * HIDD, bb1 + (size_t)i * HIDD,
                                                      W2t + (size_t)i * HD * HIDD, b2 + (size_t)i * HD,
                                                      N);
    }

    // pooling + classifier
    pool_kernel<<<G, 256, 0, stream>>>(h, batch, N, pooled);
    cls_kernel<<<(G * 2 + 255) / 256, 256, 0, stream>>>(pooled, cls_W, cls_b, out, G);
}

// Round 3
// 567.442 us; speedup vs baseline: 2.2975x; 1.3229x over previous
//
#include <hip/hip_runtime.h>
#include <hip/hip_bf16.h>

#define HD 128
#define HIDD 256
#define EPS_MSG 1e-7f
#define EPS_SM 1e-16f
#define LN_EPS 1e-5f
#define NEG_BIG -3.402823466e38f
#define AP 136   // A_lds row stride (bf16 elems)
#define HP 264   // hm_lds row stride (bf16 elems)

typedef __attribute__((ext_vector_type(8))) short bf16x8;
typedef __attribute__((ext_vector_type(4))) float f32x4;

static __device__ __forceinline__ float wave_reduce_sum(float v) {
#pragma unroll
    for (int off = 32; off >= 1; off >>= 1) v += __shfl_xor(v, off, 64);
    return v;
}

static __device__ __forceinline__ float bf2f(ushort u) {
    union { float f; unsigned v; } x;
    x.v = ((unsigned)u) << 16;
    return x.f;
}
static __device__ __forceinline__ float u2f(unsigned v) {
    union { float f; unsigned u; } x;
    x.u = v;
    return x.f;
}
static __device__ __forceinline__ ushort f2bf(float f) {
    __hip_bfloat16 b = __float2bfloat16(f);
    return *(ushort*)&b;
}

// ---------------- fused encoder + layer-0 LN+ReLU ----------------
// h = x @ enc_W + enc_b ; zp = pack(relu(LN(h)))
__global__ __launch_bounds__(256) void enc_ln_kernel(const float* __restrict__ x,
                                                     const float* __restrict__ W,
                                                     const float* __restrict__ b,
                                                     const float* __restrict__ g,
                                                     const float* __restrict__ bt,
                                                     float* __restrict__ h,
                                                     unsigned* __restrict__ zp, int N) {
    int node = blockIdx.x * 4 + (threadIdx.x >> 6);
    int lane = threadIdx.x & 63;
    if (node >= N) return;
    float xr[7];
#pragma unroll
    for (int j = 0; j < 7; ++j) xr[j] = x[node * 7 + j];
    float v0 = b[lane], v1 = b[lane + 64];
#pragma unroll
    for (int j = 0; j < 7; ++j) {
        v0 = fmaf(xr[j], W[j * HD + lane], v0);
        v1 = fmaf(xr[j], W[j * HD + lane + 64], v1);
    }
    size_t base = (size_t)node * HD;
    h[base + lane] = v0;
    h[base + lane + 64] = v1;
    float s = wave_reduce_sum(v0 + v1);
    float ss = wave_reduce_sum(v0 * v0 + v1 * v1);
    float mu = s * (1.f / 128.f);
    float var = ss * (1.f / 128.f) - mu * mu;
    float rstd = rsqrtf(var + LN_EPS);
    float z0 = fmaxf((v0 - mu) * rstd * g[lane] + bt[lane], 0.f);
    float z1 = fmaxf((v1 - mu) * rstd * g[lane + 64] + bt[lane + 64], 0.f);
    zp[node * 64 + lane] = (unsigned)f2bf(z0) | ((unsigned)f2bf(z1) << 16);
}

// ---------------- weight convert + transpose to bf16 ----------------
__global__ __launch_bounds__(256) void wconv_kernel(const float* __restrict__ W1,
                                                    const float* __restrict__ W2,
                                                    ushort* __restrict__ W1t,
                                                    ushort* __restrict__ W2t, int L) {
    int gid = blockIdx.x * 256 + threadIdx.x;
    int per = HD * HIDD;  // 32768
    int tot = L * per;
    if (gid < tot) {
        int l = gid / per, r = gid % per;
        int n = r >> 7, k = r & 127;  // n<256, k<128
        W1t[gid] = f2bf(W1[(size_t)l * per + (size_t)k * HIDD + n]);
    } else if (gid < 2 * tot) {
        int g2 = gid - tot;
        int l = g2 / per, r = g2 % per;
        int n = r >> 8, k = r & 255;  // n<128, k<256
        W2t[g2] = f2bf(W2[(size_t)l * per + (size_t)k * HD + n]);
    }
}

// ---------------- CSR build ----------------
__global__ __launch_bounds__(256) void count_kernel(const int* __restrict__ dst, int* __restrict__ cnt, int E) {
    int e = blockIdx.x * 256 + threadIdx.x;
    if (e < E) atomicAdd(&cnt[dst[e]], 1);
}

__global__ __launch_bounds__(256) void scanA_kernel(const int* __restrict__ cnt, int* __restrict__ row_ptr,
                                                    int* __restrict__ blk_sums, int n) {
    __shared__ int sb[256];
    int tid = threadIdx.x;
    int idx = blockIdx.x * 256 + tid;
    int v = (idx < n) ? cnt[idx] : 0;
    sb[tid] = v;
    __syncthreads();
#pragma unroll
    for (int off = 1; off < 256; off <<= 1) {
        int x = (tid >= off) ? sb[tid - off] : 0;
        __syncthreads();
        sb[tid] += x;
        __syncthreads();
    }
    if (idx < n) row_ptr[idx + 1] = sb[tid];
    if (tid == 255) blk_sums[blockIdx.x] = sb[255];
}

__global__ __launch_bounds__(256) void scanB_kernel(int* __restrict__ blk_sums, int nblk) {
    __shared__ int sb[256];
    int tid = threadIdx.x;
    int v = (tid < nblk) ? blk_sums[tid] : 0;
    sb[tid] = v;
    __syncthreads();
#pragma unroll
    for (int off = 1; off < 256; off <<= 1) {
        int x = (tid >= off) ? sb[tid - off] : 0;
        __syncthreads();
        sb[tid] += x;
        __syncthreads();
    }
    if (tid < nblk) blk_sums[tid] = sb[tid];
}

__global__ __launch_bounds__(256) void scanC_kernel(int* __restrict__ row_ptr, const int* __restrict__ blk_sums, int n) {
    int idx = blockIdx.x * 256 + threadIdx.x;
    if (idx == 0) row_ptr[0] = 0;
    if (idx < n) {
        int b = idx >> 8;
        if (b > 0) row_ptr[idx + 1] += blk_sums[b - 1];
    }
}

__global__ __launch_bounds__(256) void cursor_init_kernel(const int* __restrict__ row_ptr, int* __restrict__ cursor, int n) {
    int idx = blockIdx.x * 256 + threadIdx.x;
    if (idx < n) cursor[idx] = row_ptr[idx];
}

__global__ __launch_bounds__(256) void scatter_kernel(const int* __restrict__ src, const int* __restrict__ dst,
                                                      int* __restrict__ cursor, int* __restrict__ esrc, int E) {
    int e = blockIdx.x * 256 + threadIdx.x;
    if (e < E) {
        int v = dst[e];
        int pos = atomicAdd(&cursor[v], 1);
        esrc[pos] = src[e];
    }
}

// ---------------- pre-layer LN + ReLU: zp = pack(relu(LN(h))) ----------------
__global__ __launch_bounds__(256) void ln_relu_kernel(const float* __restrict__ h,
                                                      const float* __restrict__ g,
                                                      const float* __restrict__ b,
                                                      unsigned* __restrict__ zp, int N) {
    int node = blockIdx.x * 4 + (threadIdx.x >> 6);
    int lane = threadIdx.x & 63;
    if (node >= N) return;
    const float* hr = h + (size_t)node * HD;
    float v0 = hr[lane], v1 = hr[lane + 64];
    float s = wave_reduce_sum(v0 + v1);
    float ss = wave_reduce_sum(v0 * v0 + v1 * v1);
    float mu = s * (1.f / 128.f);
    float var = ss * (1.f / 128.f) - mu * mu;
    float rstd = rsqrtf(var + LN_EPS);
    float z0 = fmaxf((v0 - mu) * rstd * g[lane] + b[lane], 0.f);
    float z1 = fmaxf((v1 - mu) * rstd * g[lane + 64] + b[lane + 64], 0.f);
    zp[node * 64 + lane] = (unsigned)f2bf(z0) | ((unsigned)f2bf(z1) << 16);
}

// ---------------- aggregation: obuf = softmax-agg(z[src]+eps) + z ----------------
__global__ __launch_bounds__(256) void agg_kernel(const unsigned* __restrict__ zp,
                                                  const int* __restrict__ row_ptr,
                                                  const int* __restrict__ esrc,
                                                  const float* __restrict__ t_all, int layer,
                                                  ushort* __restrict__ obuf, int N) {
    int node = __builtin_amdgcn_readfirstlane(blockIdx.x * 4 + (threadIdx.x >> 6));
    int lane = threadIdx.x & 63;
    if (node >= N) return;
    const float tv = t_all[layer];
    int beg = row_ptr[node], end = row_ptr[node + 1];
    float m0 = NEG_BIG, m1 = NEG_BIG;
    float se0 = 0.f, se1 = 0.f, sw0 = 0.f, sw1 = 0.f;
    int e = beg;
    if ((end - beg) & 1) {
        unsigned p = zp[(size_t)esrc[e] * 64 + lane];
        float a0 = u2f(p << 16) + EPS_MSG;
        float a1 = u2f(p & 0xffff0000u) + EPS_MSG;
        m0 = a0 * tv;
        m1 = a1 * tv;
        se0 = 1.f; se1 = 1.f;
        sw0 = a0; sw1 = a1;
        ++e;
    }
    for (; e < end; e += 2) {
        int sA = esrc[e], sB = esrc[e + 1];
        unsigned pA = zp[(size_t)sA * 64 + lane];
        unsigned pB = zp[(size_t)sB * 64 + lane];
        float a0 = u2f(pA << 16) + EPS_MSG;
        float a1 = u2f(pA & 0xffff0000u) + EPS_MSG;
        float b0 = u2f(pB << 16) + EPS_MSG;
        float b1 = u2f(pB & 0xffff0000u) + EPS_MSG;
        float lA0 = a0 * tv, lA1 = a1 * tv;
        float lB0 = b0 * tv, lB1 = b1 * tv;
        float nm0 = fmaxf(m0, fmaxf(lA0, lB0));
        float nm1 = fmaxf(m1, fmaxf(lA1, lB1));
        float sc0 = __expf(m0 - nm0), sc1 = __expf(m1 - nm1);
        float eA0 = __expf(lA0 - nm0), eA1 = __expf(lA1 - nm1);
        float eB0 = __expf(lB0 - nm0), eB1 = __expf(lB1 - nm1);
        se0 = fmaf(se0, sc0, eA0 + eB0);
        se1 = fmaf(se1, sc1, eA1 + eB1);
        sw0 = fmaf(sw0, sc0, fmaf(eA0, a0, eB0 * b0));
        sw1 = fmaf(sw1, sc1, fmaf(eA1, a1, eB1 * b1));
        m0 = nm0;
        m1 = nm1;
    }
    float a0 = (end > beg) ? sw0 / (se0 + EPS_SM) : 0.f;
    float a1 = (end > beg) ? sw1 / (se1 + EPS_SM) : 0.f;
    unsigned ps = zp[node * 64 + lane];
    float z0 = u2f(ps << 16), z1 = u2f(ps & 0xffff0000u);
    size_t base = (size_t)node * HD;
    obuf[base + lane] = f2bf(a0 + z0);
    obuf[base + lane + 64] = f2bf(a1 + z1);
}

// ---------------- fused MFMA MLP: h += relu(LN(obuf@W1+b1))@W2 + b2 ----------------
__global__ __launch_bounds__(256) void mlp_kernel(const ushort* __restrict__ obuf,
                                                  float* __restrict__ h,
                                                  const ushort* __restrict__ W1t, const float* __restrict__ b1,
                                                  const float* __restrict__ g1, const float* __restrict__ bb1,
                                                  const ushort* __restrict__ W2t, const float* __restrict__ b2,
                                                  int N) {
    __shared__ ushort s_a[64 * AP];    // 17408 B
    __shared__ ushort s_hm[64 * HP];   // 33792 B
    __shared__ float s_part[64 * 8];   // 2048 B

    int tid = threadIdx.x;
    int row0 = blockIdx.x * 64;
    int wid = tid >> 6, lane = tid & 63;
    int l15 = lane & 15, q = lane >> 4;

    // ---- stage A tile (64 x 128 bf16) ----
#pragma unroll
    for (int i = 0; i < 4; ++i) {
        int c = tid + i * 256;
        int r = c >> 4, col8 = (c & 15) * 8;
        bf16x8 v;
        if (row0 + r < N) {
            v = *(const bf16x8*)(obuf + (size_t)(row0 + r) * HD + col8);
        } else {
            v = (bf16x8)0;
        }
        *(bf16x8*)&s_a[r * AP + col8] = v;
    }
    __syncthreads();

    // ---- GEMM1 ----
    f32x4 acc1[4][4];
#pragma unroll
    for (int mb = 0; mb < 4; ++mb)
#pragma unroll
        for (int nb = 0; nb < 4; ++nb) acc1[mb][nb] = (f32x4)0.f;

#pragma unroll
    for (int kk = 0; kk < 4; ++kk) {
        bf16x8 af[4];
#pragma unroll
        for (int mb = 0; mb < 4; ++mb)
            af[mb] = *(const bf16x8*)&s_a[(mb * 16 + l15) * AP + kk * 32 + q * 8];
#pragma unroll
        for (int nb = 0; nb < 4; ++nb) {
            int col = wid * 64 + nb * 16 + l15;
            bf16x8 bf = *(const bf16x8*)&W1t[(size_t)col * HD + kk * 32 + q * 8];
#pragma unroll
            for (int mb = 0; mb < 4; ++mb)
                acc1[mb][nb] = __builtin_amdgcn_mfma_f32_16x16x32_bf16(af[mb], bf, acc1[mb][nb], 0, 0, 0);
        }
    }

    float b1c[4], g1c[4], bbc[4];
#pragma unroll
    for (int nb = 0; nb < 4; ++nb) {
        int col = wid * 64 + nb * 16 + l15;
        b1c[nb] = b1[col];
        g1c[nb] = g1[col];
        bbc[nb] = bb1[col];
#pragma unroll
        for (int mb = 0; mb < 4; ++mb) {
#pragma unroll
            for (int rg = 0; rg < 4; ++rg) acc1[mb][nb][rg] += b1c[nb];
        }
    }

    // ---- LN partial sums ----
#pragma unroll
    for (int mb = 0; mb < 4; ++mb) {
#pragma unroll
        for (int rg = 0; rg < 4; ++rg) {
            float s = acc1[mb][0][rg] + acc1[mb][1][rg] + acc1[mb][2][rg] + acc1[mb][3][rg];
            float ss = acc1[mb][0][rg] * acc1[mb][0][rg] + acc1[mb][1][rg] * acc1[mb][1][rg] +
                       acc1[mb][2][rg] * acc1[mb][2][rg] + acc1[mb][3][rg] * acc1[mb][3][rg];
#pragma unroll
            for (int m = 1; m <= 8; m <<= 1) {
                s += __shfl_xor(s, m, 64);
                ss += __shfl_xor(ss, m, 64);
            }
            if (l15 == 0) {
                int r = mb * 16 + q * 4 + rg;
                s_part[r * 8 + wid * 2] = s;
                s_part[r * 8 + wid * 2 + 1] = ss;
            }
        }
    }
    __syncthreads();

    // ---- finish LN + ReLU -> s_hm ----
#pragma unroll
    for (int mb = 0; mb < 4; ++mb) {
#pragma unroll
        for (int rg = 0; rg < 4; ++rg) {
            int r = mb * 16 + q * 4 + rg;
            f32x4 p0 = *(const f32x4*)&s_part[r * 8];
            f32x4 p1 = *(const f32x4*)&s_part[r * 8 + 4];
            float S = p0.x + p0.z + p1.x + p1.z;
            float SS = p0.y + p0.w + p1.y + p1.w;
            float mu = S * (1.f / 256.f);
            float var = SS * (1.f / 256.f) - mu * mu;
            float rstd = rsqrtf(var + LN_EPS);
#pragma unroll
            for (int nb = 0; nb < 4; ++nb) {
                float v = (acc1[mb][nb][rg] - mu) * rstd * g1c[nb] + bbc[nb];
                v = fmaxf(v, 0.f);
                s_hm[r * HP + wid * 64 + nb * 16 + l15] = f2bf(v);
            }
        }
    }
    __syncthreads();

    // ---- GEMM2 ----
    f32x4 acc2[4][2];
#pragma unroll
    for (int mb = 0; mb < 4; ++mb)
#pragma unroll
        for (int nb = 0; nb < 2; ++nb) acc2[mb][nb] = (f32x4)0.f;

#pragma unroll
    for (int kk = 0; kk < 8; ++kk) {
        bf16x8 af2[4];
#pragma unroll
        for (int mb = 0; mb < 4; ++mb)
            af2[mb] = *(const bf16x8*)&s_hm[(mb * 16 + l15) * HP + kk * 32 + q * 8];
#pragma unroll
        for (int nb = 0; nb < 2; ++nb) {
            int col = wid * 32 + nb * 16 + l15;
            bf16x8 bf = *(const bf16x8*)&W2t[(size_t)col * HIDD + kk * 32 + q * 8];
#pragma unroll
            for (int mb = 0; mb < 4; ++mb)
                acc2[mb][nb] = __builtin_amdgcn_mfma_f32_16x16x32_bf16(af2[mb], bf, acc2[mb][nb], 0, 0, 0);
        }
    }

    // ---- epilogue: h += out + b2 ----
#pragma unroll
    for (int nb = 0; nb < 2; ++nb) {
        int col = wid * 32 + nb * 16 + l15;
        float b2c = b2[col];
#pragma unroll
        for (int mb = 0; mb < 4; ++mb) {
#pragma unroll
            for (int rg = 0; rg < 4; ++rg) {
                int row = row0 + mb * 16 + q * 4 + rg;
                if (row < N) h[(size_t)row * HD + col] += acc2[mb][nb][rg] + b2c;
            }
        }
    }
}

// ---------------- pooling (sorted batch) ----------------
__global__ __launch_bounds__(256) void pool_kernel(const float* __restrict__ h,
                                                   const int* __restrict__ batch, int N,
                                                   float* __restrict__ pooled) {
    __shared__ int sb[2];
    __shared__ float red[256];
    int g = blockIdx.x;
    if (threadIdx.x == 0) {
        int lo = 0, hi = N;
        while (lo < hi) { int mid = (lo + hi) >> 1; if (batch[mid] < g) lo = mid + 1; else hi = mid; }
        sb[0] = lo;
        lo = 0; hi = N;
        int gq = g + 1;
        while (lo < hi) { int mid = (lo + hi) >> 1; if (batch[mid] < gq) lo = mid + 1; else hi = mid; }
        sb[1] = lo;
    }
    __syncthreads();
    int beg = sb[0], end = sb[1];
    int c = threadIdx.x & 127, half = threadIdx.x >> 7;
    float acc = 0.f;
    for (int r = beg + half; r < end; r += 2) acc += h[(size_t)r * HD + c];
    red[threadIdx.x] = acc;
    __syncthreads();
    if (half == 0) pooled[(size_t)g * HD + c] = red[c] + red[128 + c];
}

// ---------------- classifier ----------------
__global__ __launch_bounds__(256) void cls_kernel(const float* __restrict__ pooled,
                                                  const float* __restrict__ W,
                                                  const float* __restrict__ b,
                                                  float* __restrict__ out, int G) {
    int gid = blockIdx.x * 256 + threadIdx.x;
    if (gid >= G * 2) return;
    int g = gid >> 1, cl = gid & 1;
    float acc = b[cl];
#pragma unroll 8
    for (int k = 0; k < HD; ++k) acc += pooled[g * HD + k] * W[k * 2 + cl];
    out[gid] = acc;
}

extern "C" void kernel_launch(void* const* d_in, const int* in_sizes, int n_in,
                              void* d_out, int out_size, void* d_ws, size_t ws_size,
                              hipStream_t stream) {
    const float* x     = (const float*)d_in[0];
    const int*   eidx  = (const int*)d_in[1];
    const int*   batch = (const int*)d_in[2];
    const float* enc_W = (const float*)d_in[3];
    const float* enc_b = (const float*)d_in[4];
    const float* t_all = (const float*)d_in[5];
    const float* W1    = (const float*)d_in[6];
    const float* b1    = (const float*)d_in[7];
    const float* g1    = (const float*)d_in[8];
    const float* bb1   = (const float*)d_in[9];
    const float* W2    = (const float*)d_in[10];
    const float* b2    = (const float*)d_in[11];
    const float* ln_g  = (const float*)d_in[12];
    const float* ln_b  = (const float*)d_in[13];
    const float* cls_W = (const float*)d_in[14];
    const float* cls_b = (const float*)d_in[15];
    float* out = (float*)d_out;

    const int N = in_sizes[0] / 7;
    const int E = in_sizes[1] / 2;
    const int L = in_sizes[5];
    const int G = out_size / 2;
    const int* src = eidx;
    const int* dst = eidx + E;

    char* p = (char*)d_ws;
    auto alloc = [&](size_t bytes) {
        char* q = p;
        p += (bytes + 255) & ~(size_t)255;
        return q;
    };
    float*    h      = (float*)alloc((size_t)N * HD * 4);
    unsigned* zp     = (unsigned*)alloc((size_t)N * 64 * 4);
    ushort*   obuf   = (ushort*)alloc((size_t)N * HD * 2);
    float*    pooled = (float*)alloc((size_t)G * HD * 4);
    int* cnt      = (int*)alloc((size_t)N * 4);
    int* row_ptr  = (int*)alloc((size_t)(N + 1) * 4);
    int* cursor   = (int*)alloc((size_t)N * 4);
    int* blk_sums = (int*)alloc(256 * 4);
    int* esrc     = (int*)alloc((size_t)E * 4);
    ushort* W1t   = (ushort*)alloc((size_t)L * HD * HIDD * 2);
    ushort* W2t   = (ushort*)alloc((size_t)L * HD * HIDD * 2);

    const int nblkN = (N + 255) / 256;
    const int nblkE = (E + 255) / 256;

    // fused encoder + layer-0 LN/ReLU, weight conversion
    enc_ln_kernel<<<(N + 3) / 4, 256, 0, stream>>>(x, enc_W, enc_b, ln_g, ln_b, h, zp, N);
    {
        int tot2 = 2 * L * HD * HIDD;
        wconv_kernel<<<(tot2 + 255) / 256, 256, 0, stream>>>(W1, W2, W1t, W2t, L);
    }

    // CSR build
    hipMemsetAsync(cnt, 0, (size_t)N * 4, stream);
    count_kernel<<<nblkE, 256, 0, stream>>>(dst, cnt, E);
    scanA_kernel<<<nblkN, 256, 0, stream>>>(cnt, row_ptr, blk_sums, N);
    scanB_kernel<<<1, 256, 0, stream>>>(blk_sums, nblkN);
    scanC_kernel<<<nblkN, 256, 0, stream>>>(row_ptr, blk_sums, N);
    cursor_init_kernel<<<nblkN, 256, 0, stream>>>(row_ptr, cursor, N);
    scatter_kernel<<<nblkE, 256, 0, stream>>>(src, dst, cursor, esrc, E);

    // layers
    for (int i = 0; i < L; ++i) {
        if (i > 0)
            ln_relu_kernel<<<(N + 3) / 4, 256, 0, stream>>>(h, ln_g + i * HD, ln_b + i * HD, zp, N);
        agg_kernel<<<(N + 3) / 4, 256, 0, stream>>>(zp, row_ptr, esrc, t_all, i, obuf, N);
        mlp_kernel<<<(N + 63) / 64, 256, 0, stream>>>(obuf, h,
                                                      W1t + (size_t)i * HD * HIDD, b1 + (size_t)i * HIDD,
                                                      g1 + (size_t)i * HIDD, bb1 + (size_t)i * HIDD,
                                                      W2t + (size_t)i * HD * HIDD, b2 + (size_t)i * HD,
                                                      N);
    }

    // pooling + classifier
    pool_kernel<<<G, 256, 0, stream>>>(h, batch, N, pooled);
    cls_kernel<<<(G * 2 + 255) / 256, 256, 0, stream>>>(pooled, cls_W, cls_b, out, G);
}

// Round 4
// 513.722 us; speedup vs baseline: 2.5378x; 1.1046x over previous
//
#include <hip/hip_runtime.h>
#include <hip/hip_bf16.h>

#define HD 128
#define HIDD 256
#define EPS_MSG 1e-7f
#define EPS_SM 1e-16f
#define LN_EPS 1e-5f
#define NEG_BIG -3.402823466e38f
#define HP 264      // s_hm row stride (bf16 elems)
#define OS 136      // s_out row stride (f32 elems), 16B-aligned

typedef __attribute__((ext_vector_type(8))) short bf16x8;
typedef __attribute__((ext_vector_type(4))) float f32x4;

static __device__ __forceinline__ float wave_reduce_sum(float v) {
#pragma unroll
    for (int off = 32; off >= 1; off >>= 1) v += __shfl_xor(v, off, 64);
    return v;
}

static __device__ __forceinline__ float u2f(unsigned v) {
    union { float f; unsigned u; } x;
    x.u = v;
    return x.f;
}
static __device__ __forceinline__ ushort f2bf(float f) {
    __hip_bfloat16 b = __float2bfloat16(f);
    return *(ushort*)&b;
}
static __device__ __forceinline__ unsigned packbf(float lo, float hi) {
    return (unsigned)f2bf(lo) | ((unsigned)f2bf(hi) << 16);
}

// ---------------- fused encoder + layer-0 LN+ReLU ----------------
// h = x @ enc_W + enc_b ; zp[node][i] = pack(bf(z[2i]), bf(z[2i+1]))
__global__ __launch_bounds__(256) void enc_ln_kernel(const float* __restrict__ x,
                                                     const float* __restrict__ W,
                                                     const float* __restrict__ b,
                                                     const float* __restrict__ g,
                                                     const float* __restrict__ bt,
                                                     float* __restrict__ h,
                                                     unsigned* __restrict__ zp, int N) {
    int node = blockIdx.x * 4 + (threadIdx.x >> 6);
    int lane = threadIdx.x & 63;
    if (node >= N) return;
    float xr[7];
#pragma unroll
    for (int j = 0; j < 7; ++j) xr[j] = x[node * 7 + j];
    float v0 = b[lane], v1 = b[lane + 64];
#pragma unroll
    for (int j = 0; j < 7; ++j) {
        v0 = fmaf(xr[j], W[j * HD + lane], v0);
        v1 = fmaf(xr[j], W[j * HD + lane + 64], v1);
    }
    size_t base = (size_t)node * HD;
    h[base + lane] = v0;
    h[base + lane + 64] = v1;
    float s = wave_reduce_sum(v0 + v1);
    float ss = wave_reduce_sum(v0 * v0 + v1 * v1);
    float mu = s * (1.f / 128.f);
    float var = ss * (1.f / 128.f) - mu * mu;
    float rstd = rsqrtf(var + LN_EPS);
    float z0 = fmaxf((v0 - mu) * rstd * g[lane] + bt[lane], 0.f);       // channel lane
    float z1 = fmaxf((v1 - mu) * rstd * g[lane + 64] + bt[lane + 64], 0.f); // channel lane+64
    // repack to adjacent-pair layout: lane l stores channels (2l, 2l+1)
    float e_lo = __shfl(z0, (2 * lane) & 63);
    float o_lo = __shfl(z0, (2 * lane + 1) & 63);
    float e_hi = __shfl(z1, (2 * lane) & 63);
    float o_hi = __shfl(z1, (2 * lane + 1) & 63);
    float ce = (lane < 32) ? e_lo : e_hi;
    float co = (lane < 32) ? o_lo : o_hi;
    zp[(size_t)node * 64 + lane] = packbf(ce, co);
}

// ---------------- weight convert + transpose to bf16 ----------------
__global__ __launch_bounds__(256) void wconv_kernel(const float* __restrict__ W1,
                                                    const float* __restrict__ W2,
                                                    ushort* __restrict__ W1t,
                                                    ushort* __restrict__ W2t, int L) {
    int gid = blockIdx.x * 256 + threadIdx.x;
    int per = HD * HIDD;  // 32768
    int tot = L * per;
    if (gid < tot) {
        int l = gid / per, r = gid % per;
        int n = r >> 7, k = r & 127;  // n<256, k<128
        W1t[gid] = f2bf(W1[(size_t)l * per + (size_t)k * HIDD + n]);
    } else if (gid < 2 * tot) {
        int g2 = gid - tot;
        int l = g2 / per, r = g2 % per;
        int n = r >> 8, k = r & 255;  // n<128, k<256
        W2t[g2] = f2bf(W2[(size_t)l * per + (size_t)k * HD + n]);
    }
}

// ---------------- CSR build ----------------
__global__ __launch_bounds__(256) void count_kernel(const int* __restrict__ dst, int* __restrict__ cnt, int E) {
    int e = blockIdx.x * 256 + threadIdx.x;
    if (e < E) atomicAdd(&cnt[dst[e]], 1);
}

__global__ __launch_bounds__(256) void scanA_kernel(const int* __restrict__ cnt, int* __restrict__ row_ptr,
                                                    int* __restrict__ blk_sums, int n) {
    __shared__ int sb[256];
    int tid = threadIdx.x;
    int idx = blockIdx.x * 256 + tid;
    int v = (idx < n) ? cnt[idx] : 0;
    sb[tid] = v;
    __syncthreads();
#pragma unroll
    for (int off = 1; off < 256; off <<= 1) {
        int x = (tid >= off) ? sb[tid - off] : 0;
        __syncthreads();
        sb[tid] += x;
        __syncthreads();
    }
    if (idx < n) row_ptr[idx + 1] = sb[tid];
    if (tid == 255) blk_sums[blockIdx.x] = sb[255];
}

__global__ __launch_bounds__(256) void scanB_kernel(int* __restrict__ blk_sums, int nblk) {
    __shared__ int sb[256];
    int tid = threadIdx.x;
    int v = (tid < nblk) ? blk_sums[tid] : 0;
    sb[tid] = v;
    __syncthreads();
#pragma unroll
    for (int off = 1; off < 256; off <<= 1) {
        int x = (tid >= off) ? sb[tid - off] : 0;
        __syncthreads();
        sb[tid] += x;
        __syncthreads();
    }
    if (tid < nblk) blk_sums[tid] = sb[tid];
}

__global__ __launch_bounds__(256) void scanC_kernel(int* __restrict__ row_ptr, const int* __restrict__ blk_sums, int n) {
    int idx = blockIdx.x * 256 + threadIdx.x;
    if (idx == 0) row_ptr[0] = 0;
    if (idx < n) {
        int b = idx >> 8;
        if (b > 0) row_ptr[idx + 1] += blk_sums[b - 1];
    }
}

__global__ __launch_bounds__(256) void cursor_init_kernel(const int* __restrict__ row_ptr, int* __restrict__ cursor, int n) {
    int idx = blockIdx.x * 256 + threadIdx.x;
    if (idx < n) cursor[idx] = row_ptr[idx];
}

__global__ __launch_bounds__(256) void scatter_kernel(const int* __restrict__ src, const int* __restrict__ dst,
                                                      int* __restrict__ cursor, int* __restrict__ esrc, int E) {
    int e = blockIdx.x * 256 + threadIdx.x;
    if (e < E) {
        int v = dst[e];
        int pos = atomicAdd(&cursor[v], 1);
        esrc[pos] = src[e];
    }
}

// ---------------- aggregation: obuf = softmax-agg(z[src]+eps) + z ----------------
// zp dword i of a node = channels (2i, 2i+1) packed bf16
__global__ __launch_bounds__(256) void agg_kernel(const unsigned* __restrict__ zp,
                                                  const int* __restrict__ row_ptr,
                                                  const int* __restrict__ esrc,
                                                  const float* __restrict__ t_all, int layer,
                                                  unsigned* __restrict__ obuf, int N) {
    int node = __builtin_amdgcn_readfirstlane(blockIdx.x * 4 + (threadIdx.x >> 6));
    int lane = threadIdx.x & 63;
    if (node >= N) return;
    const float tv = t_all[layer];
    int beg = row_ptr[node], end = row_ptr[node + 1];
    float m0 = NEG_BIG, m1 = NEG_BIG;
    float se0 = 0.f, se1 = 0.f, sw0 = 0.f, sw1 = 0.f;
    int e = beg;
    if ((end - beg) & 1) {
        unsigned p = zp[(size_t)esrc[e] * 64 + lane];
        float a0 = u2f(p << 16) + EPS_MSG;
        float a1 = u2f(p & 0xffff0000u) + EPS_MSG;
        m0 = a0 * tv;
        m1 = a1 * tv;
        se0 = 1.f; se1 = 1.f;
        sw0 = a0; sw1 = a1;
        ++e;
    }
    for (; e < end; e += 2) {
        int sA = esrc[e], sB = esrc[e + 1];
        unsigned pA = zp[(size_t)sA * 64 + lane];
        unsigned pB = zp[(size_t)sB * 64 + lane];
        float a0 = u2f(pA << 16) + EPS_MSG;
        float a1 = u2f(pA & 0xffff0000u) + EPS_MSG;
        float b0 = u2f(pB << 16) + EPS_MSG;
        float b1 = u2f(pB & 0xffff0000u) + EPS_MSG;
        float lA0 = a0 * tv, lA1 = a1 * tv;
        float lB0 = b0 * tv, lB1 = b1 * tv;
        float nm0 = fmaxf(m0, fmaxf(lA0, lB0));
        float nm1 = fmaxf(m1, fmaxf(lA1, lB1));
        float sc0 = __expf(m0 - nm0), sc1 = __expf(m1 - nm1);
        float eA0 = __expf(lA0 - nm0), eA1 = __expf(lA1 - nm1);
        float eB0 = __expf(lB0 - nm0), eB1 = __expf(lB1 - nm1);
        se0 = fmaf(se0, sc0, eA0 + eB0);
        se1 = fmaf(se1, sc1, eA1 + eB1);
        sw0 = fmaf(sw0, sc0, fmaf(eA0, a0, eB0 * b0));
        sw1 = fmaf(sw1, sc1, fmaf(eA1, a1, eB1 * b1));
        m0 = nm0;
        m1 = nm1;
    }
    float a0 = (end > beg) ? sw0 / (se0 + EPS_SM) : 0.f;
    float a1 = (end > beg) ? sw1 / (se1 + EPS_SM) : 0.f;
    unsigned ps = zp[(size_t)node * 64 + lane];
    float z0 = u2f(ps << 16), z1 = u2f(ps & 0xffff0000u);
    obuf[(size_t)node * 64 + lane] = packbf(a0 + z0, a1 + z1);
}

// ---------------- fused MFMA MLP: h += relu(LN(obuf@W1+b1))@W2 + b2 ; optional next-layer z ----------------
__global__ __launch_bounds__(256) void mlp_kernel(const ushort* __restrict__ obuf,
                                                  float* __restrict__ h,
                                                  const ushort* __restrict__ W1t, const float* __restrict__ b1,
                                                  const float* __restrict__ g1, const float* __restrict__ bb1,
                                                  const ushort* __restrict__ W2t, const float* __restrict__ b2,
                                                  const float* __restrict__ gnext, const float* __restrict__ btnext,
                                                  unsigned* __restrict__ zp, int fuse,
                                                  int N) {
    __shared__ char smem[64 * OS * 4];   // 34816 B; aliases s_hm (64*264*2 = 33792)
    __shared__ float s_part[64 * 8];     // 2048 B
    ushort* s_hm = (ushort*)smem;
    float* s_out = (float*)smem;

    int tid = threadIdx.x;
    int row0 = blockIdx.x * 64;
    int wid = tid >> 6, lane = tid & 63;
    int l15 = lane & 15, q = lane >> 4;

    // ---- GEMM1: u = A @ W1 + b1 (A-fragments loaded directly from global) ----
    f32x4 acc1[4][4];
#pragma unroll
    for (int mb = 0; mb < 4; ++mb)
#pragma unroll
        for (int nb = 0; nb < 4; ++nb) acc1[mb][nb] = (f32x4)0.f;

#pragma unroll
    for (int kk = 0; kk < 4; ++kk) {
        bf16x8 af[4];
#pragma unroll
        for (int mb = 0; mb < 4; ++mb) {
            int row = row0 + mb * 16 + l15;
            if (row < N)
                af[mb] = *(const bf16x8*)(obuf + (size_t)row * HD + kk * 32 + q * 8);
            else
                af[mb] = (bf16x8)0;
        }
#pragma unroll
        for (int nb = 0; nb < 4; ++nb) {
            int col = wid * 64 + nb * 16 + l15;
            bf16x8 bf = *(const bf16x8*)&W1t[(size_t)col * HD + kk * 32 + q * 8];
#pragma unroll
            for (int mb = 0; mb < 4; ++mb)
                acc1[mb][nb] = __builtin_amdgcn_mfma_f32_16x16x32_bf16(af[mb], bf, acc1[mb][nb], 0, 0, 0);
        }
    }

    float b1c[4], g1c[4], bbc[4];
#pragma unroll
    for (int nb = 0; nb < 4; ++nb) {
        int col = wid * 64 + nb * 16 + l15;
        b1c[nb] = b1[col];
        g1c[nb] = g1[col];
        bbc[nb] = bb1[col];
#pragma unroll
        for (int mb = 0; mb < 4; ++mb) {
#pragma unroll
            for (int rg = 0; rg < 4; ++rg) acc1[mb][nb][rg] += b1c[nb];
        }
    }

    // ---- LN partial sums (per wave: 64 of 256 cols per row) ----
#pragma unroll
    for (int mb = 0; mb < 4; ++mb) {
#pragma unroll
        for (int rg = 0; rg < 4; ++rg) {
            float s = acc1[mb][0][rg] + acc1[mb][1][rg] + acc1[mb][2][rg] + acc1[mb][3][rg];
            float ss = acc1[mb][0][rg] * acc1[mb][0][rg] + acc1[mb][1][rg] * acc1[mb][1][rg] +
                       acc1[mb][2][rg] * acc1[mb][2][rg] + acc1[mb][3][rg] * acc1[mb][3][rg];
#pragma unroll
            for (int m = 1; m <= 8; m <<= 1) {
                s += __shfl_xor(s, m, 64);
                ss += __shfl_xor(ss, m, 64);
            }
            if (l15 == 0) {
                int r = mb * 16 + q * 4 + rg;
                s_part[r * 8 + wid * 2] = s;
                s_part[r * 8 + wid * 2 + 1] = ss;
            }
        }
    }
    __syncthreads();

    // ---- finish LN + ReLU -> s_hm (bf16) ----
#pragma unroll
    for (int mb = 0; mb < 4; ++mb) {
#pragma unroll
        for (int rg = 0; rg < 4; ++rg) {
            int r = mb * 16 + q * 4 + rg;
            f32x4 p0 = *(const f32x4*)&s_part[r * 8];
            f32x4 p1 = *(const f32x4*)&s_part[r * 8 + 4];
            float S = p0.x + p0.z + p1.x + p1.z;
            float SS = p0.y + p0.w + p1.y + p1.w;
            float mu = S * (1.f / 256.f);
            float var = SS * (1.f / 256.f) - mu * mu;
            float rstd = rsqrtf(var + LN_EPS);
#pragma unroll
            for (int nb = 0; nb < 4; ++nb) {
                float v = (acc1[mb][nb][rg] - mu) * rstd * g1c[nb] + bbc[nb];
                v = fmaxf(v, 0.f);
                s_hm[r * HP + wid * 64 + nb * 16 + l15] = f2bf(v);
            }
        }
    }
    __syncthreads();

    // ---- GEMM2: out = hm @ W2 ----
    f32x4 acc2[4][2];
#pragma unroll
    for (int mb = 0; mb < 4; ++mb)
#pragma unroll
        for (int nb = 0; nb < 2; ++nb) acc2[mb][nb] = (f32x4)0.f;

#pragma unroll
    for (int kk = 0; kk < 8; ++kk) {
        bf16x8 af2[4];
#pragma unroll
        for (int mb = 0; mb < 4; ++mb)
            af2[mb] = *(const bf16x8*)&s_hm[(mb * 16 + l15) * HP + kk * 32 + q * 8];
#pragma unroll
        for (int nb = 0; nb < 2; ++nb) {
            int col = wid * 32 + nb * 16 + l15;
            bf16x8 bf = *(const bf16x8*)&W2t[(size_t)col * HIDD + kk * 32 + q * 8];
#pragma unroll
            for (int mb = 0; mb < 4; ++mb)
                acc2[mb][nb] = __builtin_amdgcn_mfma_f32_16x16x32_bf16(af2[mb], bf, acc2[mb][nb], 0, 0, 0);
        }
    }
    __syncthreads();  // all s_hm reads done; safe to overwrite as s_out

    // ---- stage out+b2 to s_out (f32) ----
#pragma unroll
    for (int nb = 0; nb < 2; ++nb) {
        int col = wid * 32 + nb * 16 + l15;
        float b2c = b2[col];
#pragma unroll
        for (int mb = 0; mb < 4; ++mb) {
#pragma unroll
            for (int rg = 0; rg < 4; ++rg) {
                int r = mb * 16 + q * 4 + rg;
                s_out[r * OS + col] = acc2[mb][nb][rg] + b2c;
            }
        }
    }
    __syncthreads();

    // ---- coalesced flush: h += out ; optional fused next-layer LN+ReLU -> zp ----
    int rr = tid >> 3;   // 0..31
    int c8 = tid & 7;    // 0..7
    f32x4 gv[4], bv[4];
    if (fuse) {
#pragma unroll
        for (int jj = 0; jj < 4; ++jj) {
            int c4 = c8 + 8 * jj;
            gv[jj] = *(const f32x4*)&gnext[c4 * 4];
            bv[jj] = *(const f32x4*)&btnext[c4 * 4];
        }
    }
#pragma unroll
    for (int ph = 0; ph < 2; ++ph) {
        int r = rr + 32 * ph;
        int grow = row0 + r;
        if (grow < N) {
            f32x4 hv[4];
            float s = 0.f, ss = 0.f;
#pragma unroll
            for (int jj = 0; jj < 4; ++jj) {
                int c4 = c8 + 8 * jj;
                f32x4 ho = *(const f32x4*)&h[(size_t)grow * HD + c4 * 4];
                f32x4 ov = *(const f32x4*)&s_out[r * OS + c4 * 4];
                f32x4 hn;
#pragma unroll
                for (int k = 0; k < 4; ++k) hn[k] = ho[k] + ov[k];
                *(f32x4*)&h[(size_t)grow * HD + c4 * 4] = hn;
                hv[jj] = hn;
#pragma unroll
                for (int k = 0; k < 4; ++k) { s += hn[k]; ss += hn[k] * hn[k]; }
            }
            if (fuse) {
#pragma unroll
                for (int m = 1; m <= 4; m <<= 1) {
                    s += __shfl_xor(s, m, 64);
                    ss += __shfl_xor(ss, m, 64);
                }
                float mu = s * (1.f / 128.f);
                float var = ss * (1.f / 128.f) - mu * mu;
                float rstd = rsqrtf(var + LN_EPS);
#pragma unroll
                for (int jj = 0; jj < 4; ++jj) {
                    int c4 = c8 + 8 * jj;
                    float z0 = fmaxf((hv[jj][0] - mu) * rstd * gv[jj][0] + bv[jj][0], 0.f);
                    float z1 = fmaxf((hv[jj][1] - mu) * rstd * gv[jj][1] + bv[jj][1], 0.f);
                    float z2 = fmaxf((hv[jj][2] - mu) * rstd * gv[jj][2] + bv[jj][2], 0.f);
                    float z3 = fmaxf((hv[jj][3] - mu) * rstd * gv[jj][3] + bv[jj][3], 0.f);
                    uint2 pk;
                    pk.x = packbf(z0, z1);
                    pk.y = packbf(z2, z3);
                    *(uint2*)&zp[(size_t)grow * 64 + c4 * 2] = pk;
                }
            }
        }
    }
}

// ---------------- pooling (sorted batch) ----------------
__global__ __launch_bounds__(256) void pool_kernel(const float* __restrict__ h,
                                                   const int* __restrict__ batch, int N,
                                                   float* __restrict__ pooled) {
    __shared__ int sb[2];
    __shared__ float red[256];
    int g = blockIdx.x;
    if (threadIdx.x == 0) {
        int lo = 0, hi = N;
        while (lo < hi) { int mid = (lo + hi) >> 1; if (batch[mid] < g) lo = mid + 1; else hi = mid; }
        sb[0] = lo;
        lo = 0; hi = N;
        int gq = g + 1;
        while (lo < hi) { int mid = (lo + hi) >> 1; if (batch[mid] < gq) lo = mid + 1; else hi = mid; }
        sb[1] = lo;
    }
    __syncthreads();
    int beg = sb[0], end = sb[1];
    int c = threadIdx.x & 127, half = threadIdx.x >> 7;
    float acc = 0.f;
    for (int r = beg + half; r < end; r += 2) acc += h[(size_t)r * HD + c];
    red[threadIdx.x] = acc;
    __syncthreads();
    if (half == 0) pooled[(size_t)g * HD + c] = red[c] + red[128 + c];
}

// ---------------- classifier ----------------
__global__ __launch_bounds__(256) void cls_kernel(const float* __restrict__ pooled,
                                                  const float* __restrict__ W,
                                                  const float* __restrict__ b,
                                                  float* __restrict__ out, int G) {
    int gid = blockIdx.x * 256 + threadIdx.x;
    if (gid >= G * 2) return;
    int g = gid >> 1, cl = gid & 1;
    float acc = b[cl];
#pragma unroll 8
    for (int k = 0; k < HD; ++k) acc += pooled[g * HD + k] * W[k * 2 + cl];
    out[gid] = acc;
}

extern "C" void kernel_launch(void* const* d_in, const int* in_sizes, int n_in,
                              void* d_out, int out_size, void* d_ws, size_t ws_size,
                              hipStream_t stream) {
    const float* x     = (const float*)d_in[0];
    const int*   eidx  = (const int*)d_in[1];
    const int*   batch = (const int*)d_in[2];
    const float* enc_W = (const float*)d_in[3];
    const float* enc_b = (const float*)d_in[4];
    const float* t_all = (const float*)d_in[5];
    const float* W1    = (const float*)d_in[6];
    const float* b1    = (const float*)d_in[7];
    const float* g1    = (const float*)d_in[8];
    const float* bb1   = (const float*)d_in[9];
    const float* W2    = (const float*)d_in[10];
    const float* b2    = (const float*)d_in[11];
    const float* ln_g  = (const float*)d_in[12];
    const float* ln_b  = (const float*)d_in[13];
    const float* cls_W = (const float*)d_in[14];
    const float* cls_b = (const float*)d_in[15];
    float* out = (float*)d_out;

    const int N = in_sizes[0] / 7;
    const int E = in_sizes[1] / 2;
    const int L = in_sizes[5];
    const int G = out_size / 2;
    const int* src = eidx;
    const int* dst = eidx + E;

    char* p = (char*)d_ws;
    auto alloc = [&](size_t bytes) {
        char* q = p;
        p += (bytes + 255) & ~(size_t)255;
        return q;
    };
    float*    h      = (float*)alloc((size_t)N * HD * 4);
    unsigned* zp     = (unsigned*)alloc((size_t)N * 64 * 4);
    unsigned* obuf   = (unsigned*)alloc((size_t)N * 64 * 4);
    float*    pooled = (float*)alloc((size_t)G * HD * 4);
    int* cnt      = (int*)alloc((size_t)N * 4);
    int* row_ptr  = (int*)alloc((size_t)(N + 1) * 4);
    int* cursor   = (int*)alloc((size_t)N * 4);
    int* blk_sums = (int*)alloc(256 * 4);
    int* esrc     = (int*)alloc((size_t)E * 4);
    ushort* W1t   = (ushort*)alloc((size_t)L * HD * HIDD * 2);
    ushort* W2t   = (ushort*)alloc((size_t)L * HD * HIDD * 2);

    const int nblkN = (N + 255) / 256;
    const int nblkE = (E + 255) / 256;

    // fused encoder + layer-0 LN/ReLU, weight conversion
    enc_ln_kernel<<<(N + 3) / 4, 256, 0, stream>>>(x, enc_W, enc_b, ln_g, ln_b, h, zp, N);
    {
        int tot2 = 2 * L * HD * HIDD;
        wconv_kernel<<<(tot2 + 255) / 256, 256, 0, stream>>>(W1, W2, W1t, W2t, L);
    }

    // CSR build
    hipMemsetAsync(cnt, 0, (size_t)N * 4, stream);
    count_kernel<<<nblkE, 256, 0, stream>>>(dst, cnt, E);
    scanA_kernel<<<nblkN, 256, 0, stream>>>(cnt, row_ptr, blk_sums, N);
    scanB_kernel<<<1, 256, 0, stream>>>(blk_sums, nblkN);
    scanC_kernel<<<nblkN, 256, 0, stream>>>(row_ptr, blk_sums, N);
    cursor_init_kernel<<<nblkN, 256, 0, stream>>>(row_ptr, cursor, N);
    scatter_kernel<<<nblkE, 256, 0, stream>>>(src, dst, cursor, esrc, E);

    // layers (ln_relu fused into previous mlp's epilogue)
    for (int i = 0; i < L; ++i) {
        agg_kernel<<<(N + 3) / 4, 256, 0, stream>>>(zp, row_ptr, esrc, t_all, i, obuf, N);
        int fuse = (i + 1 < L) ? 1 : 0;
        const float* gn = ln_g + (size_t)(fuse ? i + 1 : i) * HD;
        const float* bn = ln_b + (size_t)(fuse ? i + 1 : i) * HD;
        mlp_kernel<<<(N + 63) / 64, 256, 0, stream>>>((const ushort*)obuf, h,
                                                      W1t + (size_t)i * HD * HIDD, b1 + (size_t)i * HIDD,
                                                      g1 + (size_t)i * HIDD, bb1 + (size_t)i * HIDD,
                                                      W2t + (size_t)i * HD * HIDD, b2 + (size_t)i * HD,
                                                      gn, bn, zp, fuse, N);
    }

    // pooling + classifier
    pool_kernel<<<G, 256, 0, stream>>>(h, batch, N, pooled);
    cls_kernel<<<(G * 2 + 255) / 256, 256, 0, stream>>>(pooled, cls_W, cls_b, out, G);
}